// Round 10
// baseline (279.863 us; speedup 1.0000x reference)
//
#include <hip/hip_runtime.h>
#include <math.h>

#define HIDDEN 4096
#define NEXP 64
#define TOPK 8
#define MARGIN 2.5e-4f
#define KHALF 2048        // per-wave K range
#define NCH 64            // KHALF / 32
#define TPB 16            // tokens per block (2 waves, kh split)

using short8   = __attribute__((ext_vector_type(8))) short;   // 8 bf16 fragment
using floatx4  = __attribute__((ext_vector_type(4))) float;   // MFMA acc
using ushort4v = __attribute__((ext_vector_type(4))) unsigned short;
using uint4v   = __attribute__((ext_vector_type(4))) unsigned int;

// d_ws layout: [0,4) redo counter | [64, 64+64K) redo token list |
//              [128K, 640K) W_hi bf16[64][4096] | [640K, 1152K) W_lo
#define WS_LIST_OFF (64)
#define WS_WHI_OFF  (128 * 1024)
#define WS_WLO_OFF  (640 * 1024)
#define WS_NEED     (1152 * 1024)

__device__ __forceinline__ unsigned short bf16_rn(float x) {
    unsigned int u = __builtin_bit_cast(unsigned int, x);
    unsigned int r = u + 0x7FFFu + ((u >> 16) & 1u);   // round-to-nearest-even
    return (unsigned short)(r >> 16);
}
__device__ __forceinline__ float bf16_to_f(unsigned short h) {
    unsigned int u = ((unsigned int)h) << 16;
    return __builtin_bit_cast(float, u);
}

// ---------------- pass 0: split W into bf16 hi/lo (RN, runs every call) ----
__global__ void wconv_kernel(const float* __restrict__ W,
                             unsigned short* __restrict__ Whi,
                             unsigned short* __restrict__ Wlo,
                             int* __restrict__ cnt) {
    if (blockIdx.x == 0 && threadIdx.x == 0) *cnt = 0;
    int i = (blockIdx.x * 256 + threadIdx.x) * 4;
    float4 w = *reinterpret_cast<const float4*>(W + i);
    float ws4[4] = {w.x, w.y, w.z, w.w};
    unsigned short h[4], l[4];
#pragma unroll
    for (int j = 0; j < 4; ++j) {
        h[j] = bf16_rn(ws4[j]);
        l[j] = bf16_rn(ws4[j] - bf16_to_f(h[j]));
    }
    ushort4v hv = {h[0], h[1], h[2], h[3]};
    ushort4v lv = {l[0], l[1], l[2], l[3]};
    *reinterpret_cast<ushort4v*>(Whi + i) = hv;
    *reinterpret_cast<ushort4v*>(Wlo + i) = lv;
}

// ---------------- pass 1: MFMA gate — pure per-wave streaming --------------
// 128 thr = 2 waves; block owns 16 tokens x 64 experts.
// Wave kh (0/1) computes K range [kh*2048, kh*2048+2048): fully independent
// stream, DISTINCT X and W bytes (no duplication, no barriers, no LDS in the
// main loop). B fragments read straight from L2-resident Whi/Wlo (1 MB).
// 3-set rotating register prefetch, depth 2 (20 loads in flight/wave).
// launch_bounds(128,1): VGPR cap 256 so the scheduler does NOT collapse the
// pipeline (r5/r9 failure mode: VGPR 40-56 = serialized loads).
// End: 2-way kh reduce via LDS + proven margin top-9 epilogue.

#define DECL_SET(S) \
    float4 xa0_##S, xa1_##S; \
    short8 bh0_##S, bh1_##S, bh2_##S, bh3_##S; \
    short8 bl0_##S, bl1_##S, bl2_##S, bl3_##S;

#define ISSUE(S, C) do { \
    const int kb_ = (C) * 32; \
    xa0_##S = *reinterpret_cast<const float4*>(xrow + kb_); \
    xa1_##S = *reinterpret_cast<const float4*>(xrow + kb_ + 4); \
    bh0_##S = *reinterpret_cast<const short8*>(whrow + kb_); \
    bh1_##S = *reinterpret_cast<const short8*>(whrow + 16 * HIDDEN + kb_); \
    bh2_##S = *reinterpret_cast<const short8*>(whrow + 32 * HIDDEN + kb_); \
    bh3_##S = *reinterpret_cast<const short8*>(whrow + 48 * HIDDEN + kb_); \
    bl0_##S = *reinterpret_cast<const short8*>(wlrow + kb_); \
    bl1_##S = *reinterpret_cast<const short8*>(wlrow + 16 * HIDDEN + kb_); \
    bl2_##S = *reinterpret_cast<const short8*>(wlrow + 32 * HIDDEN + kb_); \
    bl3_##S = *reinterpret_cast<const short8*>(wlrow + 48 * HIDDEN + kb_); \
    __builtin_amdgcn_sched_barrier(0); \
} while (0)

#define COMPUTE(S) do { \
    short8 ah_, al_; \
    convert(xa0_##S, xa1_##S, ah_, al_); \
    acc0 = __builtin_amdgcn_mfma_f32_16x16x32_bf16(ah_, bh0_##S, acc0, 0, 0, 0); \
    acc1 = __builtin_amdgcn_mfma_f32_16x16x32_bf16(ah_, bh1_##S, acc1, 0, 0, 0); \
    acc2 = __builtin_amdgcn_mfma_f32_16x16x32_bf16(ah_, bh2_##S, acc2, 0, 0, 0); \
    acc3 = __builtin_amdgcn_mfma_f32_16x16x32_bf16(ah_, bh3_##S, acc3, 0, 0, 0); \
    acc0 = __builtin_amdgcn_mfma_f32_16x16x32_bf16(ah_, bl0_##S, acc0, 0, 0, 0); \
    acc1 = __builtin_amdgcn_mfma_f32_16x16x32_bf16(ah_, bl1_##S, acc1, 0, 0, 0); \
    acc2 = __builtin_amdgcn_mfma_f32_16x16x32_bf16(ah_, bl2_##S, acc2, 0, 0, 0); \
    acc3 = __builtin_amdgcn_mfma_f32_16x16x32_bf16(ah_, bl3_##S, acc3, 0, 0, 0); \
    acc0 = __builtin_amdgcn_mfma_f32_16x16x32_bf16(al_, bh0_##S, acc0, 0, 0, 0); \
    acc1 = __builtin_amdgcn_mfma_f32_16x16x32_bf16(al_, bh1_##S, acc1, 0, 0, 0); \
    acc2 = __builtin_amdgcn_mfma_f32_16x16x32_bf16(al_, bh2_##S, acc2, 0, 0, 0); \
    acc3 = __builtin_amdgcn_mfma_f32_16x16x32_bf16(al_, bh3_##S, acc3, 0, 0, 0); \
} while (0)

__device__ __forceinline__ void convert(const float4& a, const float4& b,
                                        short8& ah, short8& al) {
    unsigned int xu[8] = {
        __builtin_bit_cast(unsigned int, a.x), __builtin_bit_cast(unsigned int, a.y),
        __builtin_bit_cast(unsigned int, a.z), __builtin_bit_cast(unsigned int, a.w),
        __builtin_bit_cast(unsigned int, b.x), __builtin_bit_cast(unsigned int, b.y),
        __builtin_bit_cast(unsigned int, b.z), __builtin_bit_cast(unsigned int, b.w)};
    unsigned int hw[4], lw[4];
#pragma unroll
    for (int p = 0; p < 4; ++p) {
        unsigned int u0 = xu[2 * p], u1 = xu[2 * p + 1];
        hw[p] = __builtin_amdgcn_perm(u1, u0, 0x07060302u);  // hi16(u1):hi16(u0)
        float d0 = __builtin_bit_cast(float, u0) - __builtin_bit_cast(float, u0 & 0xFFFF0000u);
        float d1 = __builtin_bit_cast(float, u1) - __builtin_bit_cast(float, u1 & 0xFFFF0000u);
        lw[p] = __builtin_amdgcn_perm(__builtin_bit_cast(unsigned int, d1),
                                      __builtin_bit_cast(unsigned int, d0), 0x07060302u);
    }
    uint4v hv = {hw[0], hw[1], hw[2], hw[3]};
    uint4v lv = {lw[0], lw[1], lw[2], lw[3]};
    ah = __builtin_bit_cast(short8, hv);
    al = __builtin_bit_cast(short8, lv);
}

__global__ __launch_bounds__(128, 1)
void gate_mfma(const float* __restrict__ X,
               const unsigned short* __restrict__ Whi,
               const unsigned short* __restrict__ Wlo,
               float* __restrict__ out,
               int* __restrict__ redo_cnt, int* __restrict__ redo_list, int T) {
    __shared__ float accs[16][68];
    const int tid  = threadIdx.x;
    const int lane = tid & 63;
    const int kh   = tid >> 6;              // 0..1 K-half
    const int t0   = blockIdx.x * TPB;

    const float* xrow = X
        + (size_t)(t0 + (lane & 15)) * HIDDEN + kh * KHALF + (lane >> 4) * 8;
    const unsigned short* whrow = Whi
        + (size_t)(lane & 15) * HIDDEN + kh * KHALF + (lane >> 4) * 8;
    const unsigned short* wlrow = Wlo
        + (size_t)(lane & 15) * HIDDEN + kh * KHALF + (lane >> 4) * 8;

    floatx4 acc0 = {0.f,0.f,0.f,0.f}, acc1 = {0.f,0.f,0.f,0.f};
    floatx4 acc2 = {0.f,0.f,0.f,0.f}, acc3 = {0.f,0.f,0.f,0.f};

    DECL_SET(0) DECL_SET(1) DECL_SET(2)

    ISSUE(0, 0); ISSUE(1, 1);
#pragma unroll 1
    for (int base = 0; base < NCH - 4; base += 3) {   // base 0..57, chunks 0..59
        ISSUE(2, base + 2); COMPUTE(0);
        ISSUE(0, base + 3); COMPUTE(1);
        ISSUE(1, base + 4); COMPUTE(2);
    }
    ISSUE(2, 62); COMPUTE(0);   // chunk 60
    ISSUE(0, 63); COMPUTE(1);   // chunk 61
    COMPUTE(2);                 // chunk 62
    COMPUTE(0);                 // chunk 63

    // ---- 2-way kh reduce in LDS -------------------------------------------
    // D layout (verified r4-r9): col = lane&15 (expert), row = (lane>>4)*4+r
    const int drow = (lane >> 4) * 4;
    const int dcol = lane & 15;
    if (kh == 0) {
#pragma unroll
        for (int r = 0; r < 4; ++r) {
            accs[drow + r][ 0 + dcol] = acc0[r];
            accs[drow + r][16 + dcol] = acc1[r];
            accs[drow + r][32 + dcol] = acc2[r];
            accs[drow + r][48 + dcol] = acc3[r];
        }
    }
    __syncthreads();
    if (kh == 1) {
#pragma unroll
        for (int r = 0; r < 4; ++r) {
            accs[drow + r][ 0 + dcol] += acc0[r];
            accs[drow + r][16 + dcol] += acc1[r];
            accs[drow + r][32 + dcol] += acc2[r];
            accs[drow + r][48 + dcol] += acc3[r];
        }
    }
    __syncthreads();

    // ---- epilogue: wave kh handles token rows kh*8..kh*8+7; lane = expert --
    float* out_w = out;
    float* out_i = out + (size_t)T * TOPK;
#pragma unroll 1
    for (int m = 0; m < 8; ++m) {
        const int row = kh * 8 + m;
        const int t = t0 + row;
        float lg = accs[row][lane];
        float v = 30.0f * tanhf(lg * (1.0f / 30.0f));
        float vcur = v, vmax0 = 0.f, my_e = 0.f, sum = 0.f, prev = 0.f;
        int   my_i = 0;
        bool  ambig = false;
#pragma unroll 1
        for (int k = 0; k < TOPK + 1; ++k) {   // ranks 1..9 with margin check
            float bv = vcur;
            int   bi = lane;
#pragma unroll
            for (int s = 32; s >= 1; s >>= 1) {
                float ov = __shfl_xor(bv, s);
                int   oi = __shfl_xor(bi, s);
                if (ov > bv || (ov == bv && oi < bi)) { bv = ov; bi = oi; }
            }
            if (k == 0) vmax0 = bv;
            else        ambig |= (prev - bv < MARGIN);
            prev = bv;
            if (k < TOPK) {
                float e = __expf(bv - vmax0);
                sum += e;
                if (lane == k) { my_e = e; my_i = bi; }
                if (lane == bi) vcur = -INFINITY;
            }
        }
        if (!ambig) {
            if (lane < TOPK) {
                out_w[(size_t)t * TOPK + lane] = my_e / sum;
                out_i[(size_t)t * TOPK + lane] = (float)my_i;
            }
        } else if (lane == 0) {
            redo_list[atomicAdd(redo_cnt, 1)] = t;
        }
    }
}

// ---------------- pass 2: exact f64 redo of ambiguous tokens ---------------
__global__ __launch_bounds__(256, 2)
void gate_redo(const float* __restrict__ X, const float* __restrict__ W,
               float* __restrict__ out,
               const int* __restrict__ redo_cnt, const int* __restrict__ redo_list,
               int T) {
    __shared__ double lgs[64];
    const int lane = threadIdx.x & 63;
    const int q    = threadIdx.x >> 6;
    const int n    = *redo_cnt;
    float* out_w = out;
    float* out_i = out + (size_t)T * TOPK;

    for (int i = blockIdx.x; i < n; i += gridDim.x) {
        const int t = redo_list[i];
        const float* xr = X + (size_t)t * HIDDEN;
#pragma unroll 1
        for (int j = 0; j < 16; ++j) {
            const int e = q * 16 + j;
            const float* wr = W + (size_t)e * HIDDEN;
            double s = 0.0;
#pragma unroll 2
            for (int k = lane * 4; k < HIDDEN; k += 256) {
                float4 wv = *reinterpret_cast<const float4*>(wr + k);
                float4 xv = *reinterpret_cast<const float4*>(xr + k);
                s = fma((double)xv.x, (double)wv.x, s);
                s = fma((double)xv.y, (double)wv.y, s);
                s = fma((double)xv.z, (double)wv.z, s);
                s = fma((double)xv.w, (double)wv.w, s);
            }
#pragma unroll
            for (int sft = 32; sft >= 1; sft >>= 1) s += __shfl_xor(s, sft);
            if (lane == 0) lgs[e] = s;
        }
        __syncthreads();
        if (q == 0) {
            double vv = 30.0 * tanh(lgs[lane] * (1.0 / 30.0));
            double dmax0 = 0.0, dmy_e = 0.0, dsum = 0.0;
            int    dmy_i = 0;
#pragma unroll 1
            for (int k = 0; k < TOPK; ++k) {
                double bv = vv;
                int    bi = lane;
#pragma unroll
                for (int s = 32; s >= 1; s >>= 1) {
                    double ov = __shfl_xor(bv, s);
                    int    oi = __shfl_xor(bi, s);
                    if (ov > bv || (ov == bv && oi < bi)) { bv = ov; bi = oi; }
                }
                if (k == 0) dmax0 = bv;
                double e = exp(bv - dmax0);
                dsum += e;
                if (lane == k) { dmy_e = e; dmy_i = bi; }
                if (lane == bi) vv = -HUGE_VAL;
            }
            if (lane < TOPK) {
                out_w[(size_t)t * TOPK + lane] = (float)(dmy_e / dsum);
                out_i[(size_t)t * TOPK + lane] = (float)dmy_i;
            }
        }
        __syncthreads();
    }
}

// ---------------- fallback (round-3 proven) if ws too small ----------------
#define F_HC 64
#define F_LDS_STRIDE 68
#define F_TPW 4
#define F_TPB 16

__global__ __launch_bounds__(256, 4)
void moe_gate_fallback(const float* __restrict__ X, const float* __restrict__ W,
                       float* __restrict__ out, int T) {
    __shared__ float wlds[NEXP * F_LDS_STRIDE];
    const int tid  = threadIdx.x;
    const int lane = tid & 63;
    const int wid  = tid >> 6;
    const int t0   = blockIdx.x * F_TPB + wid * F_TPW;
    double accd[F_TPW];
#pragma unroll
    for (int m = 0; m < F_TPW; ++m) accd[m] = 0.0;
    for (int hb = 0; hb < HIDDEN; hb += F_HC) {
        __syncthreads();
#pragma unroll
        for (int k = 0; k < 4; ++k) {
            int f = tid + k * 256, e = f >> 4, c4 = f & 15;
            const float4 wv = *reinterpret_cast<const float4*>(W + e * HIDDEN + hb + c4 * 4);
            *reinterpret_cast<float4*>(&wlds[e * F_LDS_STRIDE + c4 * 4]) = wv;
        }
        __syncthreads();
        float accf[F_TPW];
#pragma unroll
        for (int m = 0; m < F_TPW; ++m) accf[m] = 0.f;
#pragma unroll 4
        for (int h4 = 0; h4 < F_HC / 4; ++h4) {
            const float4 wv = *reinterpret_cast<const float4*>(&wlds[lane * F_LDS_STRIDE + h4 * 4]);
#pragma unroll
            for (int m = 0; m < F_TPW; ++m) {
                const float4 xv = *reinterpret_cast<const float4*>(
                    X + (size_t)(t0 + m) * HIDDEN + hb + h4 * 4);
                accf[m] = fmaf(xv.x, wv.x, accf[m]);
                accf[m] = fmaf(xv.y, wv.y, accf[m]);
                accf[m] = fmaf(xv.z, wv.z, accf[m]);
                accf[m] = fmaf(xv.w, wv.w, accf[m]);
            }
        }
#pragma unroll
        for (int m = 0; m < F_TPW; ++m) accd[m] += (double)accf[m];
    }
    float* out_w = out;
    float* out_i = out + (size_t)T * TOPK;
#pragma unroll 1
    for (int m = 0; m < F_TPW; ++m) {
        const int t = t0 + m;
        double vv = 30.0 * tanh(accd[m] * (1.0 / 30.0));
        double dmax0 = 0.0, dmy_e = 0.0, dsum = 0.0;
        int dmy_i = 0;
#pragma unroll 1
        for (int k = 0; k < TOPK; ++k) {
            double bv = vv; int bi = lane;
#pragma unroll
            for (int s = 32; s >= 1; s >>= 1) {
                double ov = __shfl_xor(bv, s);
                int    oi = __shfl_xor(bi, s);
                if (ov > bv || (ov == bv && oi < bi)) { bv = ov; bi = oi; }
            }
            if (k == 0) dmax0 = bv;
            double e = exp(bv - dmax0);
            dsum += e;
            if (lane == k) { dmy_e = e; dmy_i = bi; }
            if (lane == bi) vv = -HUGE_VAL;
        }
        if (lane < TOPK) {
            out_w[(size_t)t * TOPK + lane] = (float)(dmy_e / dsum);
            out_i[(size_t)t * TOPK + lane] = (float)dmy_i;
        }
    }
}

extern "C" void kernel_launch(void* const* d_in, const int* in_sizes, int n_in,
                              void* d_out, int out_size, void* d_ws, size_t ws_size,
                              hipStream_t stream) {
    const float* X = (const float*)d_in[0];     // [4,4096,4096] fp32
    const float* W = (const float*)d_in[1];     // [64,4096] fp32
    float* out = (float*)d_out;
    const int T = in_sizes[0] / HIDDEN;         // 16384

    if (ws_size < WS_NEED) {
        hipLaunchKernelGGL(moe_gate_fallback, dim3(T / F_TPB), dim3(256), 0, stream, X, W, out, T);
        return;
    }
    char* ws = (char*)d_ws;
    int* cnt  = (int*)ws;
    int* list = (int*)(ws + WS_LIST_OFF);
    unsigned short* Whi = (unsigned short*)(ws + WS_WHI_OFF);
    unsigned short* Wlo = (unsigned short*)(ws + WS_WLO_OFF);

    hipLaunchKernelGGL(wconv_kernel, dim3(256), dim3(256), 0, stream, W, Whi, Wlo, cnt);
    hipLaunchKernelGGL(gate_mfma, dim3(T / TPB), dim3(128), 0, stream,
                       X, Whi, Wlo, out, cnt, list, T);
    hipLaunchKernelGGL(gate_redo, dim3(256), dim3(256), 0, stream,
                       X, W, out, cnt, list, T);
}

// Round 11
// 180.795 us; speedup vs baseline: 1.5480x; 1.5480x over previous
//
#include <hip/hip_runtime.h>
#include <math.h>

#define HIDDEN 4096
#define NEXP 64
#define TOPK 8
#define MARGIN 2.5e-4f
#define BK 64
#define TPB 16
#define NCHUNK (HIDDEN / BK)   // 64

using short8   = __attribute__((ext_vector_type(8))) short;   // 8 bf16 fragment
using floatx4  = __attribute__((ext_vector_type(4))) float;   // MFMA acc
using uint4v   = __attribute__((ext_vector_type(4))) unsigned int;

// d_ws: [0,4) redo counter | [64, 64+64K) redo list |
//       [128K, 640K) W'hi packed frags | [768K, 1280K) W'lo packed frags
#define WS_LIST_OFF (64)
#define WS_WHP_OFF  (128 * 1024)
#define WS_WLP_OFF  (768 * 1024)
#define WS_NEED     (1280 * 1024)

__device__ __forceinline__ unsigned short bf16_rn(float x) {
    unsigned int u = __builtin_bit_cast(unsigned int, x);
    unsigned int r = u + 0x7FFFu + ((u >> 16) & 1u);   // round-to-nearest-even
    return (unsigned short)(r >> 16);
}
__device__ __forceinline__ float bf16_to_f(unsigned short h) {
    unsigned int u = ((unsigned int)h) << 16;
    return __builtin_bit_cast(float, u);
}
__device__ __forceinline__ void gload16(const void* g, void* l) {
    __builtin_amdgcn_global_load_lds(
        (const __attribute__((address_space(1))) void*)g,
        (__attribute__((address_space(3))) void*)l, 16, 0, 0);
}

// ---- pass 0: split W into bf16 hi/lo AND pre-pack into MFMA fragment order.
// Fragment tile (c32, et): element(lane l, j): e = et*16 + (l&15),
// k = c32*32 + (l>>4)*8 + j.  Packed offset = ((c32*4 + et)*64 + l)*8 + j.
// => GEMM B-load is ONE coalesced 16B/lane load (1 KB contiguous per wave).
__global__ void wconv_kernel(const float* __restrict__ W,
                             unsigned short* __restrict__ Whp,
                             unsigned short* __restrict__ Wlp,
                             int* __restrict__ cnt) {
    if (blockIdx.x == 0 && threadIdx.x == 0) *cnt = 0;
    const int id  = blockIdx.x * 256 + threadIdx.x;    // 32768 total
    const int c32 = id >> 8;
    const int et  = (id >> 6) & 3;
    const int l   = id & 63;
    const int e   = et * 16 + (l & 15);
    const int k0  = c32 * 32 + (l >> 4) * 8;
    const float4 a = *reinterpret_cast<const float4*>(W + (size_t)e * HIDDEN + k0);
    const float4 b = *reinterpret_cast<const float4*>(W + (size_t)e * HIDDEN + k0 + 4);
    const float xs[8] = {a.x, a.y, a.z, a.w, b.x, b.y, b.z, b.w};
    short8 hv, lv;
#pragma unroll
    for (int j = 0; j < 8; ++j) {
        unsigned short h = bf16_rn(xs[j]);
        hv[j] = (short)h;
        lv[j] = (short)bf16_rn(xs[j] - bf16_to_f(h));
    }
    const size_t off = ((size_t)(c32 * 4 + et) * 64 + l) * 8;
    *reinterpret_cast<short8*>(Whp + off) = hv;
    *reinterpret_cast<short8*>(Wlp + off) = lv;
}

// ---- pass 1: MFMA gate. 256 thr = 4 waves; block = 16 tok x 64 exp.
// Wave q = expert tile (16 exp). X: LDS-staged (3 x 4KB, swizzled gload16,
// counted vmcnt — r7 skeleton). W: DIRECT coalesced frag loads from packed
// W' (L2-resident, no staging). W-frag regs double-buffered, named sets.
__device__ __forceinline__ void convert(const float4& a, const float4& b,
                                        short8& ah, short8& al) {
    const unsigned int xu[8] = {
        __builtin_bit_cast(unsigned int, a.x), __builtin_bit_cast(unsigned int, a.y),
        __builtin_bit_cast(unsigned int, a.z), __builtin_bit_cast(unsigned int, a.w),
        __builtin_bit_cast(unsigned int, b.x), __builtin_bit_cast(unsigned int, b.y),
        __builtin_bit_cast(unsigned int, b.z), __builtin_bit_cast(unsigned int, b.w)};
    unsigned int hw[4], lw[4];
#pragma unroll
    for (int p = 0; p < 4; ++p) {
        unsigned int u0 = xu[2 * p], u1 = xu[2 * p + 1];
        hw[p] = __builtin_amdgcn_perm(u1, u0, 0x07060302u);   // hi16(u1):hi16(u0)
        float d0 = __builtin_bit_cast(float, u0) - __builtin_bit_cast(float, u0 & 0xFFFF0000u);
        float d1 = __builtin_bit_cast(float, u1) - __builtin_bit_cast(float, u1 & 0xFFFF0000u);
        lw[p] = __builtin_amdgcn_perm(__builtin_bit_cast(unsigned int, d1),
                                      __builtin_bit_cast(unsigned int, d0), 0x07060302u);
    }
    uint4v hv = {hw[0], hw[1], hw[2], hw[3]};
    uint4v lv = {lw[0], lw[1], lw[2], lw[3]};
    ah = __builtin_bit_cast(short8, hv);
    al = __builtin_bit_cast(short8, lv);
}

__global__ __launch_bounds__(256, 4)
void gate_mfma(const float* __restrict__ X,
               const unsigned short* __restrict__ Whp,
               const unsigned short* __restrict__ Wlp,
               float* __restrict__ out,
               int* __restrict__ redo_cnt, int* __restrict__ redo_list, int T) {
    __shared__ __align__(16) char smem[12288];   // 3 x 4KB X buffers
    const int tid  = threadIdx.x;
    const int lane = tid & 63;
    const int q    = tid >> 6;              // 0..3 = expert tile
    const int t0   = blockIdx.x * TPB;

    // X staging: wave q stages rows 4q..4q+3 (1 gload16/chunk/wave).
    const int r_   = q * 4 + (lane >> 4);
    const int sw_  = ((lane & 15) * 16) ^ ((r_ & 7) << 4);   // rule-21 swizzle
    const float* sgsrc = X + (size_t)(t0 + r_) * HIDDEN + (sw_ >> 2);
    auto STAGE = [&](int buf, int c) {
        gload16(sgsrc + c * BK, smem + buf * 4096 + q * 1024);
    };

    // packed W bases: frag (c32, et=q): Whp + (c32*4+q)*512 + lane*8 ushorts
    const unsigned short* whb = Whp + (size_t)q * 512 + (size_t)lane * 8;
    const unsigned short* wlb = Wlp + (size_t)q * 512 + (size_t)lane * 8;
    // chunk c (BK=64) -> c32 = 2c+ks -> ushort offset c*4096 + ks*2048

#define LOADW(WH0, WL0, WH1, WL1, c) do {                                        \
    WH0 = *reinterpret_cast<const short8*>(whb + (size_t)(c) * 4096);            \
    WL0 = *reinterpret_cast<const short8*>(wlb + (size_t)(c) * 4096);            \
    WH1 = *reinterpret_cast<const short8*>(whb + (size_t)(c) * 4096 + 2048);     \
    WL1 = *reinterpret_cast<const short8*>(wlb + (size_t)(c) * 4096 + 2048);     \
} while (0)

    floatx4 acc = {0.f, 0.f, 0.f, 0.f};
    const int arow = lane & 15;
    const int asz  = (arow & 7) << 4;
    const int ab00 = ((lane >> 4) * 32) ^ asz;
    const int ab01 = ((lane >> 4) * 32 + 16) ^ asz;
    const int ab10 = (128 + (lane >> 4) * 32) ^ asz;
    const int ab11 = (128 + (lane >> 4) * 32 + 16) ^ asz;

#define COMPUTE(buf, WH0, WL0, WH1, WL1) do {                                    \
    const char* xb_ = smem + (buf) * 4096 + arow * 256;                          \
    const float4 x0_ = *reinterpret_cast<const float4*>(xb_ + ab00);             \
    const float4 x1_ = *reinterpret_cast<const float4*>(xb_ + ab01);             \
    const float4 x2_ = *reinterpret_cast<const float4*>(xb_ + ab10);             \
    const float4 x3_ = *reinterpret_cast<const float4*>(xb_ + ab11);             \
    short8 ah_, al_;                                                             \
    convert(x0_, x1_, ah_, al_);                                                 \
    acc = __builtin_amdgcn_mfma_f32_16x16x32_bf16(ah_, WH0, acc, 0, 0, 0);       \
    acc = __builtin_amdgcn_mfma_f32_16x16x32_bf16(ah_, WL0, acc, 0, 0, 0);       \
    acc = __builtin_amdgcn_mfma_f32_16x16x32_bf16(al_, WH0, acc, 0, 0, 0);       \
    convert(x2_, x3_, ah_, al_);                                                 \
    acc = __builtin_amdgcn_mfma_f32_16x16x32_bf16(ah_, WH1, acc, 0, 0, 0);       \
    acc = __builtin_amdgcn_mfma_f32_16x16x32_bf16(ah_, WL1, acc, 0, 0, 0);       \
    acc = __builtin_amdgcn_mfma_f32_16x16x32_bf16(al_, WH1, acc, 0, 0, 0);       \
} while (0)

    short8 whA0, wlA0, whA1, wlA1, whB0, wlB0, whB1, wlB1;

    // prologue: W(0) + stage(0) + stage(1); wait W(0)+st(0), keep st(1) flying
    LOADW(whA0, wlA0, whA1, wlA1, 0);
    STAGE(0, 0);
    STAGE(1, 1);
    __builtin_amdgcn_sched_barrier(0);
    asm volatile("s_waitcnt vmcnt(1)\n\ts_barrier" ::: "memory");

#pragma unroll 1
    for (int c = 0; c < NCHUNK - 2; c += 2) {
        // half 1: compute chunk c (set A), prefetch W(c+1)->B, stage(c+2)
        LOADW(whB0, wlB0, whB1, wlB1, c + 1);
        STAGE((c + 2) % 3, c + 2);
        __builtin_amdgcn_sched_barrier(0);
        COMPUTE(c % 3, whA0, wlA0, whA1, wlA1);
        asm volatile("s_waitcnt vmcnt(5)\n\ts_barrier" ::: "memory");
        // half 2: compute chunk c+1 (set B), prefetch W(c+2)->A, stage(c+3)
        LOADW(whA0, wlA0, whA1, wlA1, c + 2);
        STAGE((c + 3) % 3, c + 3);
        __builtin_amdgcn_sched_barrier(0);
        COMPUTE((c + 1) % 3, whB0, wlB0, whB1, wlB1);
        asm volatile("s_waitcnt vmcnt(5)\n\ts_barrier" ::: "memory");
    }
    // c = 62, 63 tail
    LOADW(whB0, wlB0, whB1, wlB1, NCHUNK - 1);
    __builtin_amdgcn_sched_barrier(0);
    COMPUTE((NCHUNK - 2) % 3, whA0, wlA0, whA1, wlA1);
    asm volatile("s_waitcnt vmcnt(4)\n\ts_barrier" ::: "memory");
    COMPUTE((NCHUNK - 1) % 3, whB0, wlB0, whB1, wlB1);

    __syncthreads();
    // D layout (verified r4-r10): col = lane&15 (expert), row = (lane>>4)*4+r
    float* accs = reinterpret_cast<float*>(smem);   // [16][68] overlay
    const int drow = (lane >> 4) * 4;
    const int dcol = q * 16 + (lane & 15);
#pragma unroll
    for (int r = 0; r < 4; ++r) accs[(drow + r) * 68 + dcol] = acc[r];
    __syncthreads();

    // epilogue: wave q handles token rows 4q..4q+3; lane = expert
    float* out_w = out;
    float* out_i = out + (size_t)T * TOPK;
#pragma unroll 1
    for (int m = 0; m < 4; ++m) {
        const int row = q * 4 + m;
        const int t = t0 + row;
        float lg = accs[row * 68 + lane];
        float v = 30.0f * tanhf(lg * (1.0f / 30.0f));
        float vcur = v, vmax0 = 0.f, my_e = 0.f, sum = 0.f, prev = 0.f;
        int   my_i = 0;
        bool  ambig = false;
#pragma unroll 1
        for (int k = 0; k < TOPK + 1; ++k) {   // ranks 1..9 with margin check
            float bv = vcur;
            int   bi = lane;
#pragma unroll
            for (int s = 32; s >= 1; s >>= 1) {
                float ov = __shfl_xor(bv, s);
                int   oi = __shfl_xor(bi, s);
                if (ov > bv || (ov == bv && oi < bi)) { bv = ov; bi = oi; }
            }
            if (k == 0) vmax0 = bv;
            else        ambig |= (prev - bv < MARGIN);
            prev = bv;
            if (k < TOPK) {
                float e = __expf(bv - vmax0);
                sum += e;
                if (lane == k) { my_e = e; my_i = bi; }
                if (lane == bi) vcur = -INFINITY;
            }
        }
        if (!ambig) {
            if (lane < TOPK) {
                out_w[(size_t)t * TOPK + lane] = my_e / sum;
                out_i[(size_t)t * TOPK + lane] = (float)my_i;
            }
        } else if (lane == 0) {
            redo_list[atomicAdd(redo_cnt, 1)] = t;
        }
    }
#undef LOADW
#undef COMPUTE
}

// ---- pass 2: exact f64 redo of ambiguous tokens ---------------------------
__global__ __launch_bounds__(256, 2)
void gate_redo(const float* __restrict__ X, const float* __restrict__ W,
               float* __restrict__ out,
               const int* __restrict__ redo_cnt, const int* __restrict__ redo_list,
               int T) {
    __shared__ double lgs[64];
    const int lane = threadIdx.x & 63;
    const int q    = threadIdx.x >> 6;
    const int n    = *redo_cnt;
    float* out_w = out;
    float* out_i = out + (size_t)T * TOPK;

    for (int i = blockIdx.x; i < n; i += gridDim.x) {
        const int t = redo_list[i];
        const float* xr = X + (size_t)t * HIDDEN;
#pragma unroll 1
        for (int j = 0; j < 16; ++j) {
            const int e = q * 16 + j;
            const float* wr = W + (size_t)e * HIDDEN;
            double s = 0.0;
#pragma unroll 2
            for (int k = lane * 4; k < HIDDEN; k += 256) {
                float4 wv = *reinterpret_cast<const float4*>(wr + k);
                float4 xv = *reinterpret_cast<const float4*>(xr + k);
                s = fma((double)xv.x, (double)wv.x, s);
                s = fma((double)xv.y, (double)wv.y, s);
                s = fma((double)xv.z, (double)wv.z, s);
                s = fma((double)xv.w, (double)wv.w, s);
            }
#pragma unroll
            for (int sft = 32; sft >= 1; sft >>= 1) s += __shfl_xor(s, sft);
            if (lane == 0) lgs[e] = s;
        }
        __syncthreads();
        if (q == 0) {
            double vv = 30.0 * tanh(lgs[lane] * (1.0 / 30.0));
            double dmax0 = 0.0, dmy_e = 0.0, dsum = 0.0;
            int    dmy_i = 0;
#pragma unroll 1
            for (int k = 0; k < TOPK; ++k) {
                double bv = vv;
                int    bi = lane;
#pragma unroll
                for (int s = 32; s >= 1; s >>= 1) {
                    double ov = __shfl_xor(bv, s);
                    int    oi = __shfl_xor(bi, s);
                    if (ov > bv || (ov == bv && oi < bi)) { bv = ov; bi = oi; }
                }
                if (k == 0) dmax0 = bv;
                double e = exp(bv - dmax0);
                dsum += e;
                if (lane == k) { dmy_e = e; dmy_i = bi; }
                if (lane == bi) vv = -HUGE_VAL;
            }
            if (lane < TOPK) {
                out_w[(size_t)t * TOPK + lane] = (float)(dmy_e / dsum);
                out_i[(size_t)t * TOPK + lane] = (float)dmy_i;
            }
        }
        __syncthreads();
    }
}

// ---- fallback (round-3 proven) if ws too small ----------------------------
#define F_HC 64
#define F_LDS_STRIDE 68
#define F_TPW 4
#define F_TPB 16

__global__ __launch_bounds__(256, 4)
void moe_gate_fallback(const float* __restrict__ X, const float* __restrict__ W,
                       float* __restrict__ out, int T) {
    __shared__ float wlds[NEXP * F_LDS_STRIDE];
    const int tid  = threadIdx.x;
    const int lane = tid & 63;
    const int wid  = tid >> 6;
    const int t0   = blockIdx.x * F_TPB + wid * F_TPW;
    double accd[F_TPW];
#pragma unroll
    for (int m = 0; m < F_TPW; ++m) accd[m] = 0.0;
    for (int hb = 0; hb < HIDDEN; hb += F_HC) {
        __syncthreads();
#pragma unroll
        for (int k = 0; k < 4; ++k) {
            int f = tid + k * 256, e = f >> 4, c4 = f & 15;
            const float4 wv = *reinterpret_cast<const float4*>(W + e * HIDDEN + hb + c4 * 4);
            *reinterpret_cast<float4*>(&wlds[e * F_LDS_STRIDE + c4 * 4]) = wv;
        }
        __syncthreads();
        float accf[F_TPW];
#pragma unroll
        for (int m = 0; m < F_TPW; ++m) accf[m] = 0.f;
#pragma unroll 4
        for (int h4 = 0; h4 < F_HC / 4; ++h4) {
            const float4 wv = *reinterpret_cast<const float4*>(&wlds[lane * F_LDS_STRIDE + h4 * 4]);
#pragma unroll
            for (int m = 0; m < F_TPW; ++m) {
                const float4 xv = *reinterpret_cast<const float4*>(
                    X + (size_t)(t0 + m) * HIDDEN + hb + h4 * 4);
                accf[m] = fmaf(xv.x, wv.x, accf[m]);
                accf[m] = fmaf(xv.y, wv.y, accf[m]);
                accf[m] = fmaf(xv.z, wv.z, accf[m]);
                accf[m] = fmaf(xv.w, wv.w, accf[m]);
            }
        }
#pragma unroll
        for (int m = 0; m < F_TPW; ++m) accd[m] += (double)accf[m];
    }
    float* out_w = out;
    float* out_i = out + (size_t)T * TOPK;
#pragma unroll 1
    for (int m = 0; m < F_TPW; ++m) {
        const int t = t0 + m;
        double vv = 30.0 * tanh(accd[m] * (1.0 / 30.0));
        double dmax0 = 0.0, dmy_e = 0.0, dsum = 0.0;
        int dmy_i = 0;
#pragma unroll 1
        for (int k = 0; k < TOPK; ++k) {
            double bv = vv; int bi = lane;
#pragma unroll
            for (int s = 32; s >= 1; s >>= 1) {
                double ov = __shfl_xor(bv, s);
                int    oi = __shfl_xor(bi, s);
                if (ov > bv || (ov == bv && oi < bi)) { bv = ov; bi = oi; }
            }
            if (k == 0) dmax0 = bv;
            double e = exp(bv - dmax0);
            dsum += e;
            if (lane == k) { dmy_e = e; dmy_i = bi; }
            if (lane == bi) vv = -HUGE_VAL;
        }
        if (lane < TOPK) {
            out_w[(size_t)t * TOPK + lane] = (float)(dmy_e / dsum);
            out_i[(size_t)t * TOPK + lane] = (float)dmy_i;
        }
    }
}

extern "C" void kernel_launch(void* const* d_in, const int* in_sizes, int n_in,
                              void* d_out, int out_size, void* d_ws, size_t ws_size,
                              hipStream_t stream) {
    const float* X = (const float*)d_in[0];     // [4,4096,4096] fp32
    const float* W = (const float*)d_in[1];     // [64,4096] fp32
    float* out = (float*)d_out;
    const int T = in_sizes[0] / HIDDEN;         // 16384

    if (ws_size < WS_NEED) {
        hipLaunchKernelGGL(moe_gate_fallback, dim3(T / F_TPB), dim3(256), 0, stream, X, W, out, T);
        return;
    }
    char* ws = (char*)d_ws;
    int* cnt  = (int*)ws;
    int* list = (int*)(ws + WS_LIST_OFF);
    unsigned short* Whp = (unsigned short*)(ws + WS_WHP_OFF);
    unsigned short* Wlp = (unsigned short*)(ws + WS_WLP_OFF);

    hipLaunchKernelGGL(wconv_kernel, dim3(128), dim3(256), 0, stream, W, Whp, Wlp, cnt);
    hipLaunchKernelGGL(gate_mfma, dim3(T / TPB), dim3(256), 0, stream,
                       X, Whp, Wlp, out, cnt, list, T);
    hipLaunchKernelGGL(gate_redo, dim3(256), dim3(256), 0, stream,
                       X, W, out, cnt, list, T);
}